// Round 1
// baseline (614.208 us; speedup 1.0000x reference)
//
#include <hip/hip_runtime.h>
#include <hip/hip_bf16.h>

#define N_NODES 50000
#define E0_EDGES 800000
#define E_TOTAL 850000   // E0 + self loops
#define NEG_SLOPE 0.2f
#define BN_EPS 1e-5f

__device__ __forceinline__ float lrelu(float x) { return x > 0.f ? x : NEG_SLOPE * x; }

// ---------------- CSR build ----------------
__global__ void k_zero(int* __restrict__ deg, float* __restrict__ gsum, float* __restrict__ gsumsq) {
    int i = blockIdx.x * 256 + threadIdx.x;
    if (i < N_NODES) deg[i] = 0;
    if (i < 200) { gsum[i] = 0.f; gsumsq[i] = 0.f; }
}

__global__ void k_count(const int* __restrict__ ei, int* __restrict__ deg) {
    int e = blockIdx.x * 256 + threadIdx.x;
    if (e >= E_TOTAL) return;
    int dst = (e < E0_EDGES) ? ei[E0_EDGES + e] : (e - E0_EDGES);
    atomicAdd(&deg[dst], 1);
}

__global__ void k_scanA(const int* __restrict__ deg, int* __restrict__ rowptr, int* __restrict__ bsum) {
    __shared__ int s[256];
    int i = blockIdx.x * 256 + threadIdx.x;
    int v = (i < N_NODES) ? deg[i] : 0;
    s[threadIdx.x] = v;
    __syncthreads();
    for (int off = 1; off < 256; off <<= 1) {
        int t = (threadIdx.x >= off) ? s[threadIdx.x - off] : 0;
        __syncthreads();
        s[threadIdx.x] += t;
        __syncthreads();
    }
    if (i < N_NODES) rowptr[i] = s[threadIdx.x];            // inclusive within block
    if (threadIdx.x == 255) bsum[blockIdx.x] = s[255];
}

__global__ void k_scanB(int* __restrict__ bsum, int nb) {
    __shared__ int s[256];
    int t = threadIdx.x;
    int v = (t < nb) ? bsum[t] : 0;
    s[t] = v;
    __syncthreads();
    for (int off = 1; off < 256; off <<= 1) {
        int u = (t >= off) ? s[t - off] : 0;
        __syncthreads();
        s[t] += u;
        __syncthreads();
    }
    if (t < nb) bsum[t] = s[t] - v;                         // exclusive
}

__global__ void k_scanC(const int* __restrict__ deg, int* __restrict__ rowptr,
                        const int* __restrict__ bsum, int* __restrict__ cursor) {
    int i = blockIdx.x * 256 + threadIdx.x;
    if (i >= N_NODES) return;
    int rp = bsum[blockIdx.x] + rowptr[i] - deg[i];         // exclusive global
    rowptr[i] = rp;
    cursor[i] = rp;
    if (i == N_NODES - 1) rowptr[N_NODES] = E_TOTAL;
}

__global__ void k_fill(const int* __restrict__ ei, int* __restrict__ cursor, int* __restrict__ colidx) {
    int e = blockIdx.x * 256 + threadIdx.x;
    if (e >= E_TOTAL) return;
    int src, dst;
    if (e < E0_EDGES) { src = ei[e]; dst = ei[E0_EDGES + e]; }
    else { src = e - E0_EDGES; dst = src; }
    int slot = atomicAdd(&cursor[dst], 1);
    colidx[slot] = src;
}

// ---------------- GAT layer kernels ----------------
// feat = x @ W (N x 64 @ 64 x 256), stored transposed as featT[i][d][h] (float4 per (i,d));
// el/er = per-head dots with al/ar.
__global__ void k_gemm_feat(const float* __restrict__ x, const float* __restrict__ W,
                            const float* __restrict__ al, const float* __restrict__ ar,
                            float* __restrict__ featT, float* __restrict__ el, float* __restrict__ er) {
    __shared__ float xs[8][64];
    __shared__ float fs[8][256];
    int tid = threadIdx.x;
    int row0 = blockIdx.x * 8;
    for (int i = tid; i < 8 * 64; i += 256)
        xs[i >> 6][i & 63] = x[(row0 + (i >> 6)) * 64 + (i & 63)];
    __syncthreads();
    float acc[8];
#pragma unroll
    for (int r = 0; r < 8; r++) acc[r] = 0.f;
    int c = tid;
    for (int k = 0; k < 64; k++) {
        float w = W[k * 256 + c];
#pragma unroll
        for (int r = 0; r < 8; r++) acc[r] = fmaf(xs[r][k], w, acc[r]);
    }
    float alv = al[c], arv = ar[c];     // al is [4][64], c == h*64+d
    int lane = c & 63, h = c >> 6;
#pragma unroll
    for (int r = 0; r < 8; r++) {
        float vl = acc[r] * alv, vr = acc[r] * arv;
#pragma unroll
        for (int off = 32; off; off >>= 1) {
            vl += __shfl_xor(vl, off, 64);
            vr += __shfl_xor(vr, off, 64);
        }
        if (lane == 0) {
            el[(row0 + r) * 4 + h] = vl;
            er[(row0 + r) * 4 + h] = vr;
        }
    }
#pragma unroll
    for (int r = 0; r < 8; r++) fs[r][c] = acc[r];
    __syncthreads();
    // featT[i*256 + d*4 + h]; output index j=c -> source fs[(j&3)*64 + (j>>2)]
#pragma unroll
    for (int r = 0; r < 8; r++)
        featT[(row0 + r) * 256 + c] = fs[r][((c & 3) << 6) + (c >> 2)];
}

// edge softmax (numerically stable); writes exp(e-m) per edge and 1/denom per node.
__global__ void k_attn(const float4* __restrict__ el4, const float4* __restrict__ er4,
                       const int* __restrict__ rowptr, const int* __restrict__ colidx,
                       float4* __restrict__ aw4, float4* __restrict__ denr4) {
    int tid = threadIdx.x;
    int row = blockIdx.x * 4 + (tid >> 6);
    int lane = tid & 63;
    int start = rowptr[row], end = rowptr[row + 1];
    float4 erow = er4[row];
    float4 mx = make_float4(-1e30f, -1e30f, -1e30f, -1e30f);
    for (int s = start + lane; s < end; s += 64) {
        int src = colidx[s];
        float4 e = el4[src];
        e.x = lrelu(e.x + erow.x);
        e.y = lrelu(e.y + erow.y);
        e.z = lrelu(e.z + erow.z);
        e.w = lrelu(e.w + erow.w);
        aw4[s] = e;
        mx.x = fmaxf(mx.x, e.x); mx.y = fmaxf(mx.y, e.y);
        mx.z = fmaxf(mx.z, e.z); mx.w = fmaxf(mx.w, e.w);
    }
#pragma unroll
    for (int off = 32; off; off >>= 1) {
        mx.x = fmaxf(mx.x, __shfl_xor(mx.x, off, 64));
        mx.y = fmaxf(mx.y, __shfl_xor(mx.y, off, 64));
        mx.z = fmaxf(mx.z, __shfl_xor(mx.z, off, 64));
        mx.w = fmaxf(mx.w, __shfl_xor(mx.w, off, 64));
    }
    float4 sm = make_float4(0.f, 0.f, 0.f, 0.f);
    for (int s = start + lane; s < end; s += 64) {
        float4 e = aw4[s];
        float4 ex;
        ex.x = __expf(e.x - mx.x); ex.y = __expf(e.y - mx.y);
        ex.z = __expf(e.z - mx.z); ex.w = __expf(e.w - mx.w);
        aw4[s] = ex;
        sm.x += ex.x; sm.y += ex.y; sm.z += ex.z; sm.w += ex.w;
    }
#pragma unroll
    for (int off = 32; off; off >>= 1) {
        sm.x += __shfl_xor(sm.x, off, 64);
        sm.y += __shfl_xor(sm.y, off, 64);
        sm.z += __shfl_xor(sm.z, off, 64);
        sm.w += __shfl_xor(sm.w, off, 64);
    }
    if (lane == 0) {
        float4 dr;
        dr.x = 1.f / sm.x; dr.y = 1.f / sm.y; dr.z = 1.f / sm.z; dr.w = 1.f / sm.w;
        denr4[row] = dr;
    }
}

// message aggregation + bias + relu + head-mean. One wave per node; lane = dim.
__global__ void k_aggr(const float4* __restrict__ featT4, const float4* __restrict__ aw4,
                       const float4* __restrict__ denr4, const int* __restrict__ rowptr,
                       const int* __restrict__ colidx, const float* __restrict__ bias,
                       float* __restrict__ hout) {
    int tid = threadIdx.x;
    int row = blockIdx.x * 4 + (tid >> 6);
    int lane = tid & 63;
    int start = rowptr[row], end = rowptr[row + 1];
    float4 acc = make_float4(0.f, 0.f, 0.f, 0.f);
    for (int s = start; s < end; ++s) {
        int src = colidx[s];
        float4 a = aw4[s];
        float4 f = featT4[src * 64 + lane];
        acc.x = fmaf(f.x, a.x, acc.x);
        acc.y = fmaf(f.y, a.y, acc.y);
        acc.z = fmaf(f.z, a.z, acc.z);
        acc.w = fmaf(f.w, a.w, acc.w);
    }
    float4 dr = denr4[row];
    float o = fmaxf(fmaf(acc.x, dr.x, bias[lane]), 0.f)
            + fmaxf(fmaf(acc.y, dr.y, bias[64 + lane]), 0.f)
            + fmaxf(fmaf(acc.z, dr.z, bias[128 + lane]), 0.f)
            + fmaxf(fmaf(acc.w, dr.w, bias[192 + lane]), 0.f);
    hout[row * 64 + lane] = o * 0.25f;
}

// ---------------- MLP head ----------------
__global__ void k_mlp1(const float* __restrict__ x, const float* __restrict__ W,
                       const float* __restrict__ b, float* __restrict__ z) {
    __shared__ float xs[8][64];
    int tid = threadIdx.x;
    int row0 = blockIdx.x * 8;
    for (int i = tid; i < 512; i += 256)
        xs[i >> 6][i & 63] = x[(row0 + (i >> 6)) * 64 + (i & 63)];
    __syncthreads();
    if (tid >= 200) return;
    float acc[8];
#pragma unroll
    for (int r = 0; r < 8; r++) acc[r] = 0.f;
    for (int k = 0; k < 64; k++) {
        float w = W[k * 200 + tid];
#pragma unroll
        for (int r = 0; r < 8; r++) acc[r] = fmaf(xs[r][k], w, acc[r]);
    }
    float bv = b[tid];
#pragma unroll
    for (int r = 0; r < 8; r++)
        z[(row0 + r) * 200 + tid] = fmaxf(acc[r] + bv, 0.f);
}

__global__ void k_colstats(const float* __restrict__ z, float* __restrict__ gsum, float* __restrict__ gsumsq) {
    int c = threadIdx.x;
    if (c >= 200) return;
    int rpb = (N_NODES + gridDim.x - 1) / gridDim.x;
    int r0 = blockIdx.x * rpb;
    int r1 = min(r0 + rpb, N_NODES);
    float s = 0.f, s2 = 0.f;
    for (int r = r0; r < r1; r++) {
        float v = z[r * 200 + c];
        s += v;
        s2 = fmaf(v, v, s2);
    }
    atomicAdd(&gsum[c], s);
    atomicAdd(&gsumsq[c], s2);
}

// fold BN into the final linear: w2p[c][k] = alpha_c * mw2[c][k]; b2p[k] = mb2[k] + sum_c beta_c*mw2[c][k]
__global__ void k_bnprep(const float* __restrict__ gsum, const float* __restrict__ gsumsq,
                         const float* __restrict__ bn_g, const float* __restrict__ bn_b,
                         const float* __restrict__ mw2, const float* __restrict__ mb2,
                         float* __restrict__ w2p) {
    __shared__ float red0[256], red1[256];
    int c = threadIdx.x;
    float c0 = 0.f, c1 = 0.f;
    if (c < 200) {
        const float invN = 1.f / (float)N_NODES;
        float mu = gsum[c] * invN;
        float var = gsumsq[c] * invN - mu * mu;
        float alpha = bn_g[c] * rsqrtf(var + BN_EPS);
        float beta = bn_b[c] - mu * alpha;
        float w0 = mw2[c * 2], w1 = mw2[c * 2 + 1];
        w2p[c * 2] = alpha * w0;
        w2p[c * 2 + 1] = alpha * w1;
        c0 = beta * w0;
        c1 = beta * w1;
    }
    red0[c] = c0; red1[c] = c1;
    __syncthreads();
    for (int off = 128; off; off >>= 1) {
        if (c < off) { red0[c] += red0[c + off]; red1[c] += red1[c + off]; }
        __syncthreads();
    }
    if (c == 0) {
        w2p[400] = mb2[0] + red0[0];
        w2p[401] = mb2[1] + red1[0];
    }
}

__global__ void k_final(const float* __restrict__ z, const float* __restrict__ w2p, float* __restrict__ out) {
    int tid = threadIdx.x;
    int row = blockIdx.x * 4 + (tid >> 6);
    int lane = tid & 63;
    float a0 = 0.f, a1 = 0.f;
    for (int c = lane; c < 200; c += 64) {
        float v = z[row * 200 + c];
        a0 = fmaf(v, w2p[c * 2], a0);
        a1 = fmaf(v, w2p[c * 2 + 1], a1);
    }
#pragma unroll
    for (int off = 32; off; off >>= 1) {
        a0 += __shfl_xor(a0, off, 64);
        a1 += __shfl_xor(a1, off, 64);
    }
    if (lane == 0) {
        out[row * 2] = a0 + w2p[400];
        out[row * 2 + 1] = a1 + w2p[401];
    }
}

extern "C" void kernel_launch(void* const* d_in, const int* in_sizes, int n_in,
                              void* d_out, int out_size, void* d_ws, size_t ws_size,
                              hipStream_t stream) {
    const float* features = (const float*)d_in[0];
    const int*   ei       = (const int*)d_in[1];
    const float* W1  = (const float*)d_in[2];
    const float* al1 = (const float*)d_in[3];
    const float* ar1 = (const float*)d_in[4];
    const float* b1  = (const float*)d_in[5];
    const float* W2  = (const float*)d_in[6];
    const float* al2 = (const float*)d_in[7];
    const float* ar2 = (const float*)d_in[8];
    const float* b2  = (const float*)d_in[9];
    const float* mw1 = (const float*)d_in[10];
    const float* mb1 = (const float*)d_in[11];
    const float* bng = (const float*)d_in[12];
    const float* bnb = (const float*)d_in[13];
    const float* mw2 = (const float*)d_in[14];
    const float* mb2 = (const float*)d_in[15];
    float* out = (float*)d_out;

    // ---- workspace layout (256B aligned chunks) ----
    char* base = (char*)d_ws;
    size_t off = 0;
    auto alloc = [&](size_t bytes) -> char* {
        char* p = base + off;
        off = (off + bytes + 255) & ~(size_t)255;
        return p;
    };
    int*   deg    = (int*)alloc(N_NODES * 4);
    int*   rowptr = (int*)alloc((N_NODES + 1) * 4);
    int*   cursor = (int*)alloc(N_NODES * 4);
    int*   bsum   = (int*)alloc(256 * 4);
    int*   colidx = (int*)alloc(E_TOTAL * 4);
    float4* aw4   = (float4*)alloc((size_t)E_TOTAL * 16);
    float4* denr4 = (float4*)alloc((size_t)N_NODES * 16);
    float* featT  = (float*)alloc((size_t)N_NODES * 256 * 4);
    float* el     = (float*)alloc((size_t)N_NODES * 4 * 4);
    float* er     = (float*)alloc((size_t)N_NODES * 4 * 4);
    float* h1     = (float*)alloc((size_t)N_NODES * 64 * 4);
    float* h2     = (float*)alloc((size_t)N_NODES * 64 * 4);
    float* z      = (float*)alloc((size_t)N_NODES * 200 * 4);
    float* gsum   = (float*)alloc(256 * 4);
    float* gsumsq = (float*)alloc(256 * 4);
    float* w2p    = (float*)alloc(512 * 4);
    (void)ws_size; (void)in_sizes; (void)n_in; (void)out_size;

    const int NB_N = (N_NODES + 255) / 256;   // 196
    const int NB_E = (E_TOTAL + 255) / 256;   // 3321

    // CSR build
    k_zero<<<NB_N, 256, 0, stream>>>(deg, gsum, gsumsq);
    k_count<<<NB_E, 256, 0, stream>>>(ei, deg);
    k_scanA<<<NB_N, 256, 0, stream>>>(deg, rowptr, bsum);
    k_scanB<<<1, 256, 0, stream>>>(bsum, NB_N);
    k_scanC<<<NB_N, 256, 0, stream>>>(deg, rowptr, bsum, cursor);
    k_fill<<<NB_E, 256, 0, stream>>>(ei, cursor, colidx);

    // GAT layer 1
    k_gemm_feat<<<N_NODES / 8, 256, 0, stream>>>(features, W1, al1, ar1, featT, el, er);
    k_attn<<<N_NODES / 4, 256, 0, stream>>>((const float4*)el, (const float4*)er, rowptr, colidx, aw4, denr4);
    k_aggr<<<N_NODES / 4, 256, 0, stream>>>((const float4*)featT, aw4, denr4, rowptr, colidx, b1, h1);

    // GAT layer 2
    k_gemm_feat<<<N_NODES / 8, 256, 0, stream>>>(h1, W2, al2, ar2, featT, el, er);
    k_attn<<<N_NODES / 4, 256, 0, stream>>>((const float4*)el, (const float4*)er, rowptr, colidx, aw4, denr4);
    k_aggr<<<N_NODES / 4, 256, 0, stream>>>((const float4*)featT, aw4, denr4, rowptr, colidx, b2, h2);

    // MLP head
    k_mlp1<<<N_NODES / 8, 256, 0, stream>>>(h2, mw1, mb1, z);
    k_colstats<<<512, 256, 0, stream>>>(z, gsum, gsumsq);
    k_bnprep<<<1, 256, 0, stream>>>(gsum, gsumsq, bng, bnb, mw2, mb2, w2p);
    k_final<<<N_NODES / 4, 256, 0, stream>>>(z, w2p, out);
}

// Round 2
// 459.607 us; speedup vs baseline: 1.3364x; 1.3364x over previous
//
#include <hip/hip_runtime.h>
#include <hip/hip_bf16.h>

#define N_NODES 50000
#define E0_EDGES 800000
#define E_TOTAL 850000   // E0 + self loops
#define NEG_SLOPE 0.2f
#define BN_EPS 1e-5f
#define CAP 192          // per-node LDS edge cache (fallback recompute beyond)

__device__ __forceinline__ float lrelu(float x) { return x > 0.f ? x : NEG_SLOPE * x; }

__device__ __forceinline__ ushort f2bf(float x) {
    __hip_bfloat16 b = __float2bfloat16(x);   // RNE
    return *reinterpret_cast<ushort*>(&b);
}
__device__ __forceinline__ float bf2f(ushort u) {
    return __uint_as_float(((unsigned int)u) << 16);
}

// ---------------- CSR build ----------------
__global__ void k_zero(int* __restrict__ deg, float* __restrict__ gsum, float* __restrict__ gsumsq) {
    int i = blockIdx.x * 256 + threadIdx.x;
    if (i < N_NODES) deg[i] = 0;
    if (i < 200) { gsum[i] = 0.f; gsumsq[i] = 0.f; }
}

__global__ void k_count(const int* __restrict__ ei, int* __restrict__ deg) {
    int e = blockIdx.x * 256 + threadIdx.x;
    if (e >= E_TOTAL) return;
    int dst = (e < E0_EDGES) ? ei[E0_EDGES + e] : (e - E0_EDGES);
    atomicAdd(&deg[dst], 1);
}

__global__ void k_scanA(const int* __restrict__ deg, int* __restrict__ rowptr, int* __restrict__ bsum) {
    __shared__ int s[256];
    int i = blockIdx.x * 256 + threadIdx.x;
    int v = (i < N_NODES) ? deg[i] : 0;
    s[threadIdx.x] = v;
    __syncthreads();
    for (int off = 1; off < 256; off <<= 1) {
        int t = (threadIdx.x >= off) ? s[threadIdx.x - off] : 0;
        __syncthreads();
        s[threadIdx.x] += t;
        __syncthreads();
    }
    if (i < N_NODES) rowptr[i] = s[threadIdx.x];            // inclusive within block
    if (threadIdx.x == 255) bsum[blockIdx.x] = s[255];
}

__global__ void k_scanB(int* __restrict__ bsum, int nb) {
    __shared__ int s[256];
    int t = threadIdx.x;
    int v = (t < nb) ? bsum[t] : 0;
    s[t] = v;
    __syncthreads();
    for (int off = 1; off < 256; off <<= 1) {
        int u = (t >= off) ? s[t - off] : 0;
        __syncthreads();
        s[t] += u;
        __syncthreads();
    }
    if (t < nb) bsum[t] = s[t] - v;                         // exclusive
}

__global__ void k_scanC(const int* __restrict__ deg, int* __restrict__ rowptr,
                        const int* __restrict__ bsum, int* __restrict__ cursor) {
    int i = blockIdx.x * 256 + threadIdx.x;
    if (i >= N_NODES) return;
    int rp = bsum[blockIdx.x] + rowptr[i] - deg[i];         // exclusive global
    rowptr[i] = rp;
    cursor[i] = rp;
    if (i == N_NODES - 1) rowptr[N_NODES] = E_TOTAL;
}

__global__ void k_fill(const int* __restrict__ ei, int* __restrict__ cursor, int* __restrict__ colidx) {
    int e = blockIdx.x * 256 + threadIdx.x;
    if (e >= E_TOTAL) return;
    int src, dst;
    if (e < E0_EDGES) { src = ei[e]; dst = ei[E0_EDGES + e]; }
    else { src = e - E0_EDGES; dst = src; }
    int slot = atomicAdd(&cursor[dst], 1);
    colidx[slot] = src;
}

// ---------------- GAT: x@W -> bf16 featT + el/er ----------------
// featB[i][d][h] bf16 (heads innermost); el/er [N][4] fp32.
__global__ void k_gemm_feat(const float* __restrict__ x, const float* __restrict__ W,
                            const float* __restrict__ al, const float* __restrict__ ar,
                            ushort* __restrict__ featB, float* __restrict__ el, float* __restrict__ er) {
    __shared__ float xs[8][64];
    __shared__ float fs[8][256];
    int tid = threadIdx.x;
    int row0 = blockIdx.x * 8;
    for (int i = tid; i < 8 * 64; i += 256)
        xs[i >> 6][i & 63] = x[(row0 + (i >> 6)) * 64 + (i & 63)];
    __syncthreads();
    float acc[8];
#pragma unroll
    for (int r = 0; r < 8; r++) acc[r] = 0.f;
    int c = tid;
    for (int k = 0; k < 64; k++) {
        float w = W[k * 256 + c];
#pragma unroll
        for (int r = 0; r < 8; r++) acc[r] = fmaf(xs[r][k], w, acc[r]);
    }
    float alv = al[c], arv = ar[c];     // al is [4][64], c == h*64+d
    int lane = c & 63, h = c >> 6;
#pragma unroll
    for (int r = 0; r < 8; r++) {
        float vl = acc[r] * alv, vr = acc[r] * arv;
#pragma unroll
        for (int off = 32; off; off >>= 1) {
            vl += __shfl_xor(vl, off, 64);
            vr += __shfl_xor(vr, off, 64);
        }
        if (lane == 0) {
            el[(row0 + r) * 4 + h] = vl;
            er[(row0 + r) * 4 + h] = vr;
        }
    }
#pragma unroll
    for (int r = 0; r < 8; r++) fs[r][c] = acc[r];
    __syncthreads();
    // featB[i*256 + j], j=d*4+h -> source col = (j&3)*64 + (j>>2)
#pragma unroll
    for (int r = 0; r < 8; r++)
        featB[(row0 + r) * 256 + c] = f2bf(fs[r][((c & 3) << 6) + (c >> 2)]);
}

// ---------------- merged edge-softmax + aggregation ----------------
// One wave per node. Phase1: edge-parallel logits -> max. Phase2: exp + denom
// (exp weights cached in LDS, recompute fallback past CAP). Phase3: serial edge
// loop, lane = dim, gather bf16 features (512B/edge), weighted sum, bias+relu+head-mean.
__global__ void k_gat(const float4* __restrict__ el4, const float4* __restrict__ er4,
                      const int* __restrict__ rowptr, const int* __restrict__ colidx,
                      const ushort* __restrict__ featB, const float* __restrict__ bias,
                      float* __restrict__ hout) {
    __shared__ float4 sE[4][CAP];
    __shared__ int    sSrc[4][CAP];
    int tid = threadIdx.x;
    int w = tid >> 6, lane = tid & 63;
    int row = blockIdx.x * 4 + w;
    int start = rowptr[row];
    int deg = rowptr[row + 1] - start;
    float4 erow = er4[row];

    // phase 1: logits + max
    float4 mx = make_float4(-1e30f, -1e30f, -1e30f, -1e30f);
    for (int k = 0; k * 64 < deg; k++) {
        int idx = k * 64 + lane;
        if (idx < deg) {
            int src = colidx[start + idx];
            float4 e = el4[src];
            e.x = lrelu(e.x + erow.x); e.y = lrelu(e.y + erow.y);
            e.z = lrelu(e.z + erow.z); e.w = lrelu(e.w + erow.w);
            if (idx < CAP) { sE[w][idx] = e; sSrc[w][idx] = src; }
            mx.x = fmaxf(mx.x, e.x); mx.y = fmaxf(mx.y, e.y);
            mx.z = fmaxf(mx.z, e.z); mx.w = fmaxf(mx.w, e.w);
        }
    }
#pragma unroll
    for (int off = 32; off; off >>= 1) {
        mx.x = fmaxf(mx.x, __shfl_xor(mx.x, off, 64));
        mx.y = fmaxf(mx.y, __shfl_xor(mx.y, off, 64));
        mx.z = fmaxf(mx.z, __shfl_xor(mx.z, off, 64));
        mx.w = fmaxf(mx.w, __shfl_xor(mx.w, off, 64));
    }

    // phase 2: exp + denom
    float4 sm = make_float4(0.f, 0.f, 0.f, 0.f);
    for (int k = 0; k * 64 < deg; k++) {
        int idx = k * 64 + lane;
        if (idx < deg) {
            float4 e;
            if (idx < CAP) e = sE[w][idx];
            else {
                int src = colidx[start + idx];
                e = el4[src];
                e.x = lrelu(e.x + erow.x); e.y = lrelu(e.y + erow.y);
                e.z = lrelu(e.z + erow.z); e.w = lrelu(e.w + erow.w);
            }
            float4 ex;
            ex.x = __expf(e.x - mx.x); ex.y = __expf(e.y - mx.y);
            ex.z = __expf(e.z - mx.z); ex.w = __expf(e.w - mx.w);
            if (idx < CAP) sE[w][idx] = ex;
            sm.x += ex.x; sm.y += ex.y; sm.z += ex.z; sm.w += ex.w;
        }
    }
#pragma unroll
    for (int off = 32; off; off >>= 1) {
        sm.x += __shfl_xor(sm.x, off, 64);
        sm.y += __shfl_xor(sm.y, off, 64);
        sm.z += __shfl_xor(sm.z, off, 64);
        sm.w += __shfl_xor(sm.w, off, 64);
    }
    float4 dr;
    dr.x = 1.f / sm.x; dr.y = 1.f / sm.y; dr.z = 1.f / sm.z; dr.w = 1.f / sm.w;

    // phase 3: serial edge loop, lane = dim
    const ushort4* featB4 = (const ushort4*)featB;
    float4 acc = make_float4(0.f, 0.f, 0.f, 0.f);
    for (int s = 0; s < deg; s++) {
        float4 ex; int src;
        if (s < CAP) { ex = sE[w][s]; src = sSrc[w][s]; }
        else {
            src = colidx[start + s];
            float4 e = el4[src];
            e.x = lrelu(e.x + erow.x); e.y = lrelu(e.y + erow.y);
            e.z = lrelu(e.z + erow.z); e.w = lrelu(e.w + erow.w);
            ex.x = __expf(e.x - mx.x); ex.y = __expf(e.y - mx.y);
            ex.z = __expf(e.z - mx.z); ex.w = __expf(e.w - mx.w);
        }
        ushort4 f = featB4[src * 64 + lane];
        acc.x = fmaf(bf2f(f.x), ex.x, acc.x);
        acc.y = fmaf(bf2f(f.y), ex.y, acc.y);
        acc.z = fmaf(bf2f(f.z), ex.z, acc.z);
        acc.w = fmaf(bf2f(f.w), ex.w, acc.w);
    }
    float o = fmaxf(fmaf(acc.x, dr.x, bias[lane]), 0.f)
            + fmaxf(fmaf(acc.y, dr.y, bias[64 + lane]), 0.f)
            + fmaxf(fmaf(acc.z, dr.z, bias[128 + lane]), 0.f)
            + fmaxf(fmaf(acc.w, dr.w, bias[192 + lane]), 0.f);
    hout[row * 64 + lane] = o * 0.25f;
}

// ---------------- MLP head ----------------
// GEMM + ReLU + z-write + fused BN column stats (register-accumulated).
// 250 blocks x 200 rows (25 chunks of 8); 2 atomics/col/block.
__global__ void k_mlp1_stats(const float* __restrict__ x, const float* __restrict__ W,
                             const float* __restrict__ b, float* __restrict__ z,
                             float* __restrict__ gsum, float* __restrict__ gsumsq) {
    __shared__ float xs[8][64];
    int tid = threadIdx.x;
    float bv = (tid < 200) ? b[tid] : 0.f;
    float s_ = 0.f, s2_ = 0.f;
    for (int chunk = 0; chunk < 25; chunk++) {
        int row0 = (blockIdx.x * 25 + chunk) * 8;
        for (int i = tid; i < 512; i += 256)
            xs[i >> 6][i & 63] = x[(row0 + (i >> 6)) * 64 + (i & 63)];
        __syncthreads();
        if (tid < 200) {
            float acc[8];
#pragma unroll
            for (int r = 0; r < 8; r++) acc[r] = 0.f;
            for (int k = 0; k < 64; k++) {
                float w = W[k * 200 + tid];
#pragma unroll
                for (int r = 0; r < 8; r++) acc[r] = fmaf(xs[r][k], w, acc[r]);
            }
#pragma unroll
            for (int r = 0; r < 8; r++) {
                float v = fmaxf(acc[r] + bv, 0.f);
                z[(row0 + r) * 200 + tid] = v;
                s_ += v;
                s2_ = fmaf(v, v, s2_);
            }
        }
        __syncthreads();
    }
    if (tid < 200) {
        atomicAdd(&gsum[tid], s_);
        atomicAdd(&gsumsq[tid], s2_);
    }
}

// fold BN into the final linear
__global__ void k_bnprep(const float* __restrict__ gsum, const float* __restrict__ gsumsq,
                         const float* __restrict__ bn_g, const float* __restrict__ bn_b,
                         const float* __restrict__ mw2, const float* __restrict__ mb2,
                         float* __restrict__ w2p) {
    __shared__ float red0[256], red1[256];
    int c = threadIdx.x;
    float c0 = 0.f, c1 = 0.f;
    if (c < 200) {
        const float invN = 1.f / (float)N_NODES;
        float mu = gsum[c] * invN;
        float var = gsumsq[c] * invN - mu * mu;
        float alpha = bn_g[c] * rsqrtf(var + BN_EPS);
        float beta = bn_b[c] - mu * alpha;
        float w0 = mw2[c * 2], w1 = mw2[c * 2 + 1];
        w2p[c * 2] = alpha * w0;
        w2p[c * 2 + 1] = alpha * w1;
        c0 = beta * w0;
        c1 = beta * w1;
    }
    red0[c] = c0; red1[c] = c1;
    __syncthreads();
    for (int off = 128; off; off >>= 1) {
        if (c < off) { red0[c] += red0[c + off]; red1[c] += red1[c + off]; }
        __syncthreads();
    }
    if (c == 0) {
        w2p[400] = mb2[0] + red0[0];
        w2p[401] = mb2[1] + red1[0];
    }
}

__global__ void k_final(const float* __restrict__ z, const float* __restrict__ w2p, float* __restrict__ out) {
    int tid = threadIdx.x;
    int row = blockIdx.x * 4 + (tid >> 6);
    int lane = tid & 63;
    float a0 = 0.f, a1 = 0.f;
    for (int c = lane; c < 200; c += 64) {
        float v = z[row * 200 + c];
        a0 = fmaf(v, w2p[c * 2], a0);
        a1 = fmaf(v, w2p[c * 2 + 1], a1);
    }
#pragma unroll
    for (int off = 32; off; off >>= 1) {
        a0 += __shfl_xor(a0, off, 64);
        a1 += __shfl_xor(a1, off, 64);
    }
    if (lane == 0) {
        out[row * 2] = a0 + w2p[400];
        out[row * 2 + 1] = a1 + w2p[401];
    }
}

extern "C" void kernel_launch(void* const* d_in, const int* in_sizes, int n_in,
                              void* d_out, int out_size, void* d_ws, size_t ws_size,
                              hipStream_t stream) {
    const float* features = (const float*)d_in[0];
    const int*   ei       = (const int*)d_in[1];
    const float* W1  = (const float*)d_in[2];
    const float* al1 = (const float*)d_in[3];
    const float* ar1 = (const float*)d_in[4];
    const float* b1  = (const float*)d_in[5];
    const float* W2  = (const float*)d_in[6];
    const float* al2 = (const float*)d_in[7];
    const float* ar2 = (const float*)d_in[8];
    const float* b2  = (const float*)d_in[9];
    const float* mw1 = (const float*)d_in[10];
    const float* mb1 = (const float*)d_in[11];
    const float* bng = (const float*)d_in[12];
    const float* bnb = (const float*)d_in[13];
    const float* mw2 = (const float*)d_in[14];
    const float* mb2 = (const float*)d_in[15];
    float* out = (float*)d_out;

    // ---- workspace layout ----
    char* base = (char*)d_ws;
    size_t off = 0;
    auto alloc = [&](size_t bytes) -> char* {
        char* p = base + off;
        off = (off + bytes + 255) & ~(size_t)255;
        return p;
    };
    int*    deg    = (int*)alloc(N_NODES * 4);
    int*    rowptr = (int*)alloc((N_NODES + 1) * 4);
    int*    cursor = (int*)alloc(N_NODES * 4);
    int*    bsum   = (int*)alloc(256 * 4);
    int*    colidx = (int*)alloc(E_TOTAL * 4);
    ushort* featB  = (ushort*)alloc((size_t)N_NODES * 256 * 2);
    float*  el     = (float*)alloc((size_t)N_NODES * 4 * 4);
    float*  er     = (float*)alloc((size_t)N_NODES * 4 * 4);
    float*  h1     = (float*)alloc((size_t)N_NODES * 64 * 4);
    float*  h2     = (float*)alloc((size_t)N_NODES * 64 * 4);
    float*  z      = (float*)alloc((size_t)N_NODES * 200 * 4);
    float*  gsum   = (float*)alloc(256 * 4);
    float*  gsumsq = (float*)alloc(256 * 4);
    float*  w2p    = (float*)alloc(512 * 4);
    (void)ws_size; (void)in_sizes; (void)n_in; (void)out_size;

    const int NB_N = (N_NODES + 255) / 256;   // 196
    const int NB_E = (E_TOTAL + 255) / 256;   // 3321

    // CSR build
    k_zero<<<NB_N, 256, 0, stream>>>(deg, gsum, gsumsq);
    k_count<<<NB_E, 256, 0, stream>>>(ei, deg);
    k_scanA<<<NB_N, 256, 0, stream>>>(deg, rowptr, bsum);
    k_scanB<<<1, 256, 0, stream>>>(bsum, NB_N);
    k_scanC<<<NB_N, 256, 0, stream>>>(deg, rowptr, bsum, cursor);
    k_fill<<<NB_E, 256, 0, stream>>>(ei, cursor, colidx);

    // GAT layer 1
    k_gemm_feat<<<N_NODES / 8, 256, 0, stream>>>(features, W1, al1, ar1, featB, el, er);
    k_gat<<<N_NODES / 4, 256, 0, stream>>>((const float4*)el, (const float4*)er, rowptr, colidx, featB, b1, h1);

    // GAT layer 2
    k_gemm_feat<<<N_NODES / 8, 256, 0, stream>>>(h1, W2, al2, ar2, featB, el, er);
    k_gat<<<N_NODES / 4, 256, 0, stream>>>((const float4*)el, (const float4*)er, rowptr, colidx, featB, b2, h2);

    // MLP head
    k_mlp1_stats<<<250, 256, 0, stream>>>(h2, mw1, mb1, z, gsum, gsumsq);
    k_bnprep<<<1, 256, 0, stream>>>(gsum, gsumsq, bng, bnb, mw2, mb2, w2p);
    k_final<<<N_NODES / 4, 256, 0, stream>>>(z, w2p, out);
}

// Round 3
// 438.277 us; speedup vs baseline: 1.4014x; 1.0487x over previous
//
#include <hip/hip_runtime.h>
#include <hip/hip_bf16.h>

#define N_NODES 50000
#define E0_EDGES 800000
#define E_TOTAL 850000   // E0 + self loops
#define NEG_SLOPE 0.2f
#define BN_EPS 1e-5f
#define CAP 192          // per-node LDS edge cache (fallback recompute beyond)

__device__ __forceinline__ float lrelu(float x) { return x > 0.f ? x : NEG_SLOPE * x; }

__device__ __forceinline__ ushort f2bf(float x) {
    __hip_bfloat16 b = __float2bfloat16(x);   // RNE
    return *reinterpret_cast<ushort*>(&b);
}
__device__ __forceinline__ float bf2f(ushort u) {
    return __uint_as_float(((unsigned int)u) << 16);
}

// ---------------- CSR build ----------------
__global__ void k_zero(int* __restrict__ deg, float* __restrict__ gsum, float* __restrict__ gsumsq) {
    int i = blockIdx.x * 256 + threadIdx.x;
    if (i < N_NODES) deg[i] = 0;
    if (i < 200) { gsum[i] = 0.f; gsumsq[i] = 0.f; }
}

__global__ void k_count(const int* __restrict__ ei, int* __restrict__ deg) {
    int e = blockIdx.x * 256 + threadIdx.x;
    if (e >= E_TOTAL) return;
    int dst = (e < E0_EDGES) ? ei[E0_EDGES + e] : (e - E0_EDGES);
    atomicAdd(&deg[dst], 1);
}

__global__ void k_scanA(const int* __restrict__ deg, int* __restrict__ rowptr, int* __restrict__ bsum) {
    __shared__ int s[256];
    int i = blockIdx.x * 256 + threadIdx.x;
    int v = (i < N_NODES) ? deg[i] : 0;
    s[threadIdx.x] = v;
    __syncthreads();
    for (int off = 1; off < 256; off <<= 1) {
        int t = (threadIdx.x >= off) ? s[threadIdx.x - off] : 0;
        __syncthreads();
        s[threadIdx.x] += t;
        __syncthreads();
    }
    if (i < N_NODES) rowptr[i] = s[threadIdx.x];            // inclusive within block
    if (threadIdx.x == 255) bsum[blockIdx.x] = s[255];
}

__global__ void k_scanB(int* __restrict__ bsum, int nb) {
    __shared__ int s[256];
    int t = threadIdx.x;
    int v = (t < nb) ? bsum[t] : 0;
    s[t] = v;
    __syncthreads();
    for (int off = 1; off < 256; off <<= 1) {
        int u = (t >= off) ? s[t - off] : 0;
        __syncthreads();
        s[t] += u;
        __syncthreads();
    }
    if (t < nb) bsum[t] = s[t] - v;                         // exclusive
}

__global__ void k_scanC(const int* __restrict__ deg, int* __restrict__ rowptr,
                        const int* __restrict__ bsum, int* __restrict__ cursor) {
    int i = blockIdx.x * 256 + threadIdx.x;
    if (i >= N_NODES) return;
    int rp = bsum[blockIdx.x] + rowptr[i] - deg[i];         // exclusive global
    rowptr[i] = rp;
    cursor[i] = rp;
    if (i == N_NODES - 1) rowptr[N_NODES] = E_TOTAL;
}

__global__ void k_fill(const int* __restrict__ ei, int* __restrict__ cursor, int* __restrict__ colidx) {
    int e = blockIdx.x * 256 + threadIdx.x;
    if (e >= E_TOTAL) return;
    int src, dst;
    if (e < E0_EDGES) { src = ei[e]; dst = ei[E0_EDGES + e]; }
    else { src = e - E0_EDGES; dst = src; }
    int slot = atomicAdd(&cursor[dst], 1);
    colidx[slot] = src;
}

// ---------------- GAT: x@W -> bf16 featT + el/er ----------------
// featB[i][d][h] bf16 (heads innermost); el/er [N][4] fp32.
__global__ void k_gemm_feat(const float* __restrict__ x, const float* __restrict__ W,
                            const float* __restrict__ al, const float* __restrict__ ar,
                            ushort* __restrict__ featB, float* __restrict__ el, float* __restrict__ er) {
    __shared__ float xs[8][64];
    __shared__ float fs[8][256];
    int tid = threadIdx.x;
    int row0 = blockIdx.x * 8;
    for (int i = tid; i < 8 * 64; i += 256)
        xs[i >> 6][i & 63] = x[(row0 + (i >> 6)) * 64 + (i & 63)];
    __syncthreads();
    float acc[8];
#pragma unroll
    for (int r = 0; r < 8; r++) acc[r] = 0.f;
    int c = tid;
    for (int k = 0; k < 64; k++) {
        float w = W[k * 256 + c];
#pragma unroll
        for (int r = 0; r < 8; r++) acc[r] = fmaf(xs[r][k], w, acc[r]);
    }
    float alv = al[c], arv = ar[c];     // al is [4][64], c == h*64+d
    int lane = c & 63, h = c >> 6;
#pragma unroll
    for (int r = 0; r < 8; r++) {
        float vl = acc[r] * alv, vr = acc[r] * arv;
#pragma unroll
        for (int off = 32; off; off >>= 1) {
            vl += __shfl_xor(vl, off, 64);
            vr += __shfl_xor(vr, off, 64);
        }
        if (lane == 0) {
            el[(row0 + r) * 4 + h] = vl;
            er[(row0 + r) * 4 + h] = vr;
        }
    }
#pragma unroll
    for (int r = 0; r < 8; r++) fs[r][c] = acc[r];
    __syncthreads();
    // featB[i*256 + j], j=d*4+h -> source col = (j&3)*64 + (j>>2)
#pragma unroll
    for (int r = 0; r < 8; r++)
        featB[(row0 + r) * 256 + c] = f2bf(fs[r][((c & 3) << 6) + (c >> 2)]);
}

// ---------------- merged edge-softmax + aggregation ----------------
__global__ void k_gat(const float4* __restrict__ el4, const float4* __restrict__ er4,
                      const int* __restrict__ rowptr, const int* __restrict__ colidx,
                      const ushort* __restrict__ featB, const float* __restrict__ bias,
                      float* __restrict__ hout) {
    __shared__ float4 sE[4][CAP];
    __shared__ int    sSrc[4][CAP];
    int tid = threadIdx.x;
    int w = tid >> 6, lane = tid & 63;
    int row = blockIdx.x * 4 + w;
    int start = rowptr[row];
    int deg = rowptr[row + 1] - start;
    float4 erow = er4[row];

    // phase 1: logits + max
    float4 mx = make_float4(-1e30f, -1e30f, -1e30f, -1e30f);
    for (int k = 0; k * 64 < deg; k++) {
        int idx = k * 64 + lane;
        if (idx < deg) {
            int src = colidx[start + idx];
            float4 e = el4[src];
            e.x = lrelu(e.x + erow.x); e.y = lrelu(e.y + erow.y);
            e.z = lrelu(e.z + erow.z); e.w = lrelu(e.w + erow.w);
            if (idx < CAP) { sE[w][idx] = e; sSrc[w][idx] = src; }
            mx.x = fmaxf(mx.x, e.x); mx.y = fmaxf(mx.y, e.y);
            mx.z = fmaxf(mx.z, e.z); mx.w = fmaxf(mx.w, e.w);
        }
    }
#pragma unroll
    for (int off = 32; off; off >>= 1) {
        mx.x = fmaxf(mx.x, __shfl_xor(mx.x, off, 64));
        mx.y = fmaxf(mx.y, __shfl_xor(mx.y, off, 64));
        mx.z = fmaxf(mx.z, __shfl_xor(mx.z, off, 64));
        mx.w = fmaxf(mx.w, __shfl_xor(mx.w, off, 64));
    }

    // phase 2: exp + denom
    float4 sm = make_float4(0.f, 0.f, 0.f, 0.f);
    for (int k = 0; k * 64 < deg; k++) {
        int idx = k * 64 + lane;
        if (idx < deg) {
            float4 e;
            if (idx < CAP) e = sE[w][idx];
            else {
                int src = colidx[start + idx];
                e = el4[src];
                e.x = lrelu(e.x + erow.x); e.y = lrelu(e.y + erow.y);
                e.z = lrelu(e.z + erow.z); e.w = lrelu(e.w + erow.w);
            }
            float4 ex;
            ex.x = __expf(e.x - mx.x); ex.y = __expf(e.y - mx.y);
            ex.z = __expf(e.z - mx.z); ex.w = __expf(e.w - mx.w);
            if (idx < CAP) sE[w][idx] = ex;
            sm.x += ex.x; sm.y += ex.y; sm.z += ex.z; sm.w += ex.w;
        }
    }
#pragma unroll
    for (int off = 32; off; off >>= 1) {
        sm.x += __shfl_xor(sm.x, off, 64);
        sm.y += __shfl_xor(sm.y, off, 64);
        sm.z += __shfl_xor(sm.z, off, 64);
        sm.w += __shfl_xor(sm.w, off, 64);
    }
    float4 dr;
    dr.x = 1.f / sm.x; dr.y = 1.f / sm.y; dr.z = 1.f / sm.z; dr.w = 1.f / sm.w;

    // phase 3: serial edge loop, lane = dim
    const ushort4* featB4 = (const ushort4*)featB;
    float4 acc = make_float4(0.f, 0.f, 0.f, 0.f);
    for (int s = 0; s < deg; s++) {
        float4 ex; int src;
        if (s < CAP) { ex = sE[w][s]; src = sSrc[w][s]; }
        else {
            src = colidx[start + s];
            float4 e = el4[src];
            e.x = lrelu(e.x + erow.x); e.y = lrelu(e.y + erow.y);
            e.z = lrelu(e.z + erow.z); e.w = lrelu(e.w + erow.w);
            ex.x = __expf(e.x - mx.x); ex.y = __expf(e.y - mx.y);
            ex.z = __expf(e.z - mx.z); ex.w = __expf(e.w - mx.w);
        }
        ushort4 f = featB4[src * 64 + lane];
        acc.x = fmaf(bf2f(f.x), ex.x, acc.x);
        acc.y = fmaf(bf2f(f.y), ex.y, acc.y);
        acc.z = fmaf(bf2f(f.z), ex.z, acc.z);
        acc.w = fmaf(bf2f(f.w), ex.w, acc.w);
    }
    float o = fmaxf(fmaf(acc.x, dr.x, bias[lane]), 0.f)
            + fmaxf(fmaf(acc.y, dr.y, bias[64 + lane]), 0.f)
            + fmaxf(fmaf(acc.z, dr.z, bias[128 + lane]), 0.f)
            + fmaxf(fmaf(acc.w, dr.w, bias[192 + lane]), 0.f);
    hout[row * 64 + lane] = o * 0.25f;
}

// ---------------- MLP head ----------------
// GEMM + ReLU + z-write + fused BN column stats (register-accumulated).
// 1250 blocks x 40 rows (5 chunks of 8); 2 atomics/col/block, completions staggered.
#define MLP_BLOCKS 1250
#define MLP_CHUNKS 5
__global__ void k_mlp1_stats(const float* __restrict__ x, const float* __restrict__ W,
                             const float* __restrict__ b, float* __restrict__ z,
                             float* __restrict__ gsum, float* __restrict__ gsumsq) {
    __shared__ float xs[8][64];
    int tid = threadIdx.x;
    float bv = (tid < 200) ? b[tid] : 0.f;
    float s_ = 0.f, s2_ = 0.f;
    for (int chunk = 0; chunk < MLP_CHUNKS; chunk++) {
        int row0 = (blockIdx.x * MLP_CHUNKS + chunk) * 8;
        for (int i = tid; i < 512; i += 256)
            xs[i >> 6][i & 63] = x[(row0 + (i >> 6)) * 64 + (i & 63)];
        __syncthreads();
        if (tid < 200) {
            float acc[8];
#pragma unroll
            for (int r = 0; r < 8; r++) acc[r] = 0.f;
            for (int k = 0; k < 64; k++) {
                float w = W[k * 200 + tid];
#pragma unroll
                for (int r = 0; r < 8; r++) acc[r] = fmaf(xs[r][k], w, acc[r]);
            }
#pragma unroll
            for (int r = 0; r < 8; r++) {
                float v = fmaxf(acc[r] + bv, 0.f);
                z[(row0 + r) * 200 + tid] = v;
                s_ += v;
                s2_ = fmaf(v, v, s2_);
            }
        }
        __syncthreads();
    }
    if (tid < 200) {
        atomicAdd(&gsum[tid], s_);
        atomicAdd(&gsumsq[tid], s2_);
    }
}

// fold BN into the final linear
__global__ void k_bnprep(const float* __restrict__ gsum, const float* __restrict__ gsumsq,
                         const float* __restrict__ bn_g, const float* __restrict__ bn_b,
                         const float* __restrict__ mw2, const float* __restrict__ mb2,
                         float* __restrict__ w2p) {
    __shared__ float red0[256], red1[256];
    int c = threadIdx.x;
    float c0 = 0.f, c1 = 0.f;
    if (c < 200) {
        const float invN = 1.f / (float)N_NODES;
        float mu = gsum[c] * invN;
        float var = gsumsq[c] * invN - mu * mu;
        float alpha = bn_g[c] * rsqrtf(var + BN_EPS);
        float beta = bn_b[c] - mu * alpha;
        float w0 = mw2[c * 2], w1 = mw2[c * 2 + 1];
        w2p[c * 2] = alpha * w0;
        w2p[c * 2 + 1] = alpha * w1;
        c0 = beta * w0;
        c1 = beta * w1;
    }
    red0[c] = c0; red1[c] = c1;
    __syncthreads();
    for (int off = 128; off; off >>= 1) {
        if (c < off) { red0[c] += red0[c + off]; red1[c] += red1[c + off]; }
        __syncthreads();
    }
    if (c == 0) {
        w2p[400] = mb2[0] + red0[0];
        w2p[401] = mb2[1] + red1[0];
    }
}

__global__ void k_final(const float* __restrict__ z, const float* __restrict__ w2p, float* __restrict__ out) {
    int tid = threadIdx.x;
    int row = blockIdx.x * 4 + (tid >> 6);
    int lane = tid & 63;
    float a0 = 0.f, a1 = 0.f;
    for (int c = lane; c < 200; c += 64) {
        float v = z[row * 200 + c];
        a0 = fmaf(v, w2p[c * 2], a0);
        a1 = fmaf(v, w2p[c * 2 + 1], a1);
    }
#pragma unroll
    for (int off = 32; off; off >>= 1) {
        a0 += __shfl_xor(a0, off, 64);
        a1 += __shfl_xor(a1, off, 64);
    }
    if (lane == 0) {
        out[row * 2] = a0 + w2p[400];
        out[row * 2 + 1] = a1 + w2p[401];
    }
}

extern "C" void kernel_launch(void* const* d_in, const int* in_sizes, int n_in,
                              void* d_out, int out_size, void* d_ws, size_t ws_size,
                              hipStream_t stream) {
    const float* features = (const float*)d_in[0];
    const int*   ei       = (const int*)d_in[1];
    const float* W1  = (const float*)d_in[2];
    const float* al1 = (const float*)d_in[3];
    const float* ar1 = (const float*)d_in[4];
    const float* b1  = (const float*)d_in[5];
    const float* W2  = (const float*)d_in[6];
    const float* al2 = (const float*)d_in[7];
    const float* ar2 = (const float*)d_in[8];
    const float* b2  = (const float*)d_in[9];
    const float* mw1 = (const float*)d_in[10];
    const float* mb1 = (const float*)d_in[11];
    const float* bng = (const float*)d_in[12];
    const float* bnb = (const float*)d_in[13];
    const float* mw2 = (const float*)d_in[14];
    const float* mb2 = (const float*)d_in[15];
    float* out = (float*)d_out;

    // ---- workspace layout ----
    char* base = (char*)d_ws;
    size_t off = 0;
    auto alloc = [&](size_t bytes) -> char* {
        char* p = base + off;
        off = (off + bytes + 255) & ~(size_t)255;
        return p;
    };
    int*    deg    = (int*)alloc(N_NODES * 4);
    int*    rowptr = (int*)alloc((N_NODES + 1) * 4);
    int*    cursor = (int*)alloc(N_NODES * 4);
    int*    bsum   = (int*)alloc(256 * 4);
    int*    colidx = (int*)alloc(E_TOTAL * 4);
    ushort* featB  = (ushort*)alloc((size_t)N_NODES * 256 * 2);
    float*  el     = (float*)alloc((size_t)N_NODES * 4 * 4);
    float*  er     = (float*)alloc((size_t)N_NODES * 4 * 4);
    float*  h1     = (float*)alloc((size_t)N_NODES * 64 * 4);
    float*  h2     = (float*)alloc((size_t)N_NODES * 64 * 4);
    float*  z      = (float*)alloc((size_t)N_NODES * 200 * 4);
    float*  gsum   = (float*)alloc(256 * 4);
    float*  gsumsq = (float*)alloc(256 * 4);
    float*  w2p    = (float*)alloc(512 * 4);
    (void)ws_size; (void)in_sizes; (void)n_in; (void)out_size;

    const int NB_N = (N_NODES + 255) / 256;   // 196
    const int NB_E = (E_TOTAL + 255) / 256;   // 3321

    // CSR build
    k_zero<<<NB_N, 256, 0, stream>>>(deg, gsum, gsumsq);
    k_count<<<NB_E, 256, 0, stream>>>(ei, deg);
    k_scanA<<<NB_N, 256, 0, stream>>>(deg, rowptr, bsum);
    k_scanB<<<1, 256, 0, stream>>>(bsum, NB_N);
    k_scanC<<<NB_N, 256, 0, stream>>>(deg, rowptr, bsum, cursor);
    k_fill<<<NB_E, 256, 0, stream>>>(ei, cursor, colidx);

    // GAT layer 1
    k_gemm_feat<<<N_NODES / 8, 256, 0, stream>>>(features, W1, al1, ar1, featB, el, er);
    k_gat<<<N_NODES / 4, 256, 0, stream>>>((const float4*)el, (const float4*)er, rowptr, colidx, featB, b1, h1);

    // GAT layer 2
    k_gemm_feat<<<N_NODES / 8, 256, 0, stream>>>(h1, W2, al2, ar2, featB, el, er);
    k_gat<<<N_NODES / 4, 256, 0, stream>>>((const float4*)el, (const float4*)er, rowptr, colidx, featB, b2, h2);

    // MLP head
    k_mlp1_stats<<<MLP_BLOCKS, 256, 0, stream>>>(h2, mw1, mb1, z, gsum, gsumsq);
    k_bnprep<<<1, 256, 0, stream>>>(gsum, gsumsq, bng, bnb, mw2, mb2, w2p);
    k_final<<<N_NODES / 4, 256, 0, stream>>>(z, w2p, out);
}

// Round 4
// 433.544 us; speedup vs baseline: 1.4167x; 1.0109x over previous
//
#include <hip/hip_runtime.h>
#include <hip/hip_bf16.h>

#define N_NODES 50000
#define E0_EDGES 800000
#define E_TOTAL 850000   // E0 + self loops
#define NEG_SLOPE 0.2f
#define BN_EPS 1e-5f
#define CAP 64           // per-node LDS edge cache; mean deg 17, P(deg>64)~0 (fallback correct)

__device__ __forceinline__ float lrelu(float x) { return x > 0.f ? x : NEG_SLOPE * x; }

__device__ __forceinline__ ushort f2bf(float x) {
    __hip_bfloat16 b = __float2bfloat16(x);   // RNE
    return *reinterpret_cast<ushort*>(&b);
}
__device__ __forceinline__ float bf2f(ushort u) {
    return __uint_as_float(((unsigned int)u) << 16);
}

// ---------------- CSR build ----------------
__global__ void k_zero(int* __restrict__ deg, float* __restrict__ gsum, float* __restrict__ gsumsq) {
    int i = blockIdx.x * 256 + threadIdx.x;
    if (i < N_NODES) deg[i] = 0;
    if (i < 200) { gsum[i] = 0.f; gsumsq[i] = 0.f; }
}

__global__ void k_count(const int* __restrict__ ei, int* __restrict__ deg) {
    int e = blockIdx.x * 256 + threadIdx.x;
    if (e >= E_TOTAL) return;
    int dst = (e < E0_EDGES) ? ei[E0_EDGES + e] : (e - E0_EDGES);
    atomicAdd(&deg[dst], 1);
}

__global__ void k_scanA(const int* __restrict__ deg, int* __restrict__ rowptr, int* __restrict__ bsum) {
    __shared__ int s[256];
    int i = blockIdx.x * 256 + threadIdx.x;
    int v = (i < N_NODES) ? deg[i] : 0;
    s[threadIdx.x] = v;
    __syncthreads();
    for (int off = 1; off < 256; off <<= 1) {
        int t = (threadIdx.x >= off) ? s[threadIdx.x - off] : 0;
        __syncthreads();
        s[threadIdx.x] += t;
        __syncthreads();
    }
    if (i < N_NODES) rowptr[i] = s[threadIdx.x];            // inclusive within block
    if (threadIdx.x == 255) bsum[blockIdx.x] = s[255];
}

__global__ void k_scanB(int* __restrict__ bsum, int nb) {
    __shared__ int s[256];
    int t = threadIdx.x;
    int v = (t < nb) ? bsum[t] : 0;
    s[t] = v;
    __syncthreads();
    for (int off = 1; off < 256; off <<= 1) {
        int u = (t >= off) ? s[t - off] : 0;
        __syncthreads();
        s[t] += u;
        __syncthreads();
    }
    if (t < nb) bsum[t] = s[t] - v;                         // exclusive
}

__global__ void k_scanC(const int* __restrict__ deg, int* __restrict__ rowptr,
                        const int* __restrict__ bsum, int* __restrict__ cursor) {
    int i = blockIdx.x * 256 + threadIdx.x;
    if (i >= N_NODES) return;
    int rp = bsum[blockIdx.x] + rowptr[i] - deg[i];         // exclusive global
    rowptr[i] = rp;
    cursor[i] = rp;
    if (i == N_NODES - 1) rowptr[N_NODES] = E_TOTAL;
}

__global__ void k_fill(const int* __restrict__ ei, int* __restrict__ cursor, int* __restrict__ colidx) {
    int e = blockIdx.x * 256 + threadIdx.x;
    if (e >= E_TOTAL) return;
    int src, dst;
    if (e < E0_EDGES) { src = ei[e]; dst = ei[E0_EDGES + e]; }
    else { src = e - E0_EDGES; dst = src; }
    int slot = atomicAdd(&cursor[dst], 1);
    colidx[slot] = src;
}

// ---------------- GAT: x@W -> bf16 featT + el/er ----------------
// featB[i][d][h] bf16 (heads innermost); el/er [N][4] fp32.
__global__ void k_gemm_feat(const float* __restrict__ x, const float* __restrict__ W,
                            const float* __restrict__ al, const float* __restrict__ ar,
                            ushort* __restrict__ featB, float* __restrict__ el, float* __restrict__ er) {
    __shared__ float xs[8][64];
    __shared__ float fs[8][256];
    int tid = threadIdx.x;
    int row0 = blockIdx.x * 8;
    for (int i = tid; i < 8 * 64; i += 256)
        xs[i >> 6][i & 63] = x[(row0 + (i >> 6)) * 64 + (i & 63)];
    __syncthreads();
    float acc[8];
#pragma unroll
    for (int r = 0; r < 8; r++) acc[r] = 0.f;
    int c = tid;
    for (int k = 0; k < 64; k++) {
        float w = W[k * 256 + c];
#pragma unroll
        for (int r = 0; r < 8; r++) acc[r] = fmaf(xs[r][k], w, acc[r]);
    }
    float alv = al[c], arv = ar[c];     // al is [4][64], c == h*64+d
    int lane = c & 63, h = c >> 6;
#pragma unroll
    for (int r = 0; r < 8; r++) {
        float vl = acc[r] * alv, vr = acc[r] * arv;
#pragma unroll
        for (int off = 32; off; off >>= 1) {
            vl += __shfl_xor(vl, off, 64);
            vr += __shfl_xor(vr, off, 64);
        }
        if (lane == 0) {
            el[(row0 + r) * 4 + h] = vl;
            er[(row0 + r) * 4 + h] = vr;
        }
    }
#pragma unroll
    for (int r = 0; r < 8; r++) fs[r][c] = acc[r];
    __syncthreads();
    // featB[i*256 + j], j=d*4+h -> source col = (j&3)*64 + (j>>2)
#pragma unroll
    for (int r = 0; r < 8; r++)
        featB[(row0 + r) * 256 + c] = f2bf(fs[r][((c & 3) << 6) + (c >> 2)]);
}

// ---------------- merged edge-softmax + aggregation ----------------
// One wave per node. Branchless main region [0, min(deg,CAP)) in every phase,
// rare tail (deg>CAP) recomputes. Phase-3 main loop unrolled for gather MLP.
__global__ void k_gat(const float4* __restrict__ el4, const float4* __restrict__ er4,
                      const int* __restrict__ rowptr, const int* __restrict__ colidx,
                      const ushort* __restrict__ featB, const float* __restrict__ bias,
                      float* __restrict__ hout) {
    __shared__ float4 sE[4][CAP];
    __shared__ int    sSrc[4][CAP];
    int tid = threadIdx.x;
    int w = tid >> 6, lane = tid & 63;
    int row = blockIdx.x * 4 + w;
    int start = rowptr[row];
    int deg = rowptr[row + 1] - start;
    int cached = min(deg, CAP);
    float4 erow = er4[row];

    // phase 1: logits + max (cache logits+src in LDS)
    float4 mx = make_float4(-1e30f, -1e30f, -1e30f, -1e30f);
    for (int idx = lane; idx < cached; idx += 64) {
        int src = colidx[start + idx];
        float4 e = el4[src];
        e.x = lrelu(e.x + erow.x); e.y = lrelu(e.y + erow.y);
        e.z = lrelu(e.z + erow.z); e.w = lrelu(e.w + erow.w);
        sE[w][idx] = e; sSrc[w][idx] = src;
        mx.x = fmaxf(mx.x, e.x); mx.y = fmaxf(mx.y, e.y);
        mx.z = fmaxf(mx.z, e.z); mx.w = fmaxf(mx.w, e.w);
    }
    for (int idx = CAP + lane; idx < deg; idx += 64) {      // rare tail
        int src = colidx[start + idx];
        float4 e = el4[src];
        e.x = lrelu(e.x + erow.x); e.y = lrelu(e.y + erow.y);
        e.z = lrelu(e.z + erow.z); e.w = lrelu(e.w + erow.w);
        mx.x = fmaxf(mx.x, e.x); mx.y = fmaxf(mx.y, e.y);
        mx.z = fmaxf(mx.z, e.z); mx.w = fmaxf(mx.w, e.w);
    }
#pragma unroll
    for (int off = 32; off; off >>= 1) {
        mx.x = fmaxf(mx.x, __shfl_xor(mx.x, off, 64));
        mx.y = fmaxf(mx.y, __shfl_xor(mx.y, off, 64));
        mx.z = fmaxf(mx.z, __shfl_xor(mx.z, off, 64));
        mx.w = fmaxf(mx.w, __shfl_xor(mx.w, off, 64));
    }

    // phase 2: exp + denom (overwrite LDS logits with exp weights)
    float4 sm = make_float4(0.f, 0.f, 0.f, 0.f);
    for (int idx = lane; idx < cached; idx += 64) {
        float4 e = sE[w][idx];
        float4 ex;
        ex.x = __expf(e.x - mx.x); ex.y = __expf(e.y - mx.y);
        ex.z = __expf(e.z - mx.z); ex.w = __expf(e.w - mx.w);
        sE[w][idx] = ex;
        sm.x += ex.x; sm.y += ex.y; sm.z += ex.z; sm.w += ex.w;
    }
    for (int idx = CAP + lane; idx < deg; idx += 64) {      // rare tail
        int src = colidx[start + idx];
        float4 e = el4[src];
        e.x = lrelu(e.x + erow.x); e.y = lrelu(e.y + erow.y);
        e.z = lrelu(e.z + erow.z); e.w = lrelu(e.w + erow.w);
        sm.x += __expf(e.x - mx.x); sm.y += __expf(e.y - mx.y);
        sm.z += __expf(e.z - mx.z); sm.w += __expf(e.w - mx.w);
    }
#pragma unroll
    for (int off = 32; off; off >>= 1) {
        sm.x += __shfl_xor(sm.x, off, 64);
        sm.y += __shfl_xor(sm.y, off, 64);
        sm.z += __shfl_xor(sm.z, off, 64);
        sm.w += __shfl_xor(sm.w, off, 64);
    }
    float4 dr;
    dr.x = 1.f / sm.x; dr.y = 1.f / sm.y; dr.z = 1.f / sm.z; dr.w = 1.f / sm.w;

    // phase 3: serial edge loop, lane = dim; branchless + unrolled for MLP
    const ushort4* featB4 = (const ushort4*)featB;
    float4 acc = make_float4(0.f, 0.f, 0.f, 0.f);
#pragma unroll 4
    for (int s = 0; s < cached; s++) {
        float4 ex = sE[w][s];
        int src = sSrc[w][s];
        ushort4 f = featB4[src * 64 + lane];
        acc.x = fmaf(bf2f(f.x), ex.x, acc.x);
        acc.y = fmaf(bf2f(f.y), ex.y, acc.y);
        acc.z = fmaf(bf2f(f.z), ex.z, acc.z);
        acc.w = fmaf(bf2f(f.w), ex.w, acc.w);
    }
    for (int s = CAP; s < deg; s++) {                       // rare tail
        int src = colidx[start + s];
        float4 e = el4[src];
        e.x = lrelu(e.x + erow.x); e.y = lrelu(e.y + erow.y);
        e.z = lrelu(e.z + erow.z); e.w = lrelu(e.w + erow.w);
        float4 ex;
        ex.x = __expf(e.x - mx.x); ex.y = __expf(e.y - mx.y);
        ex.z = __expf(e.z - mx.z); ex.w = __expf(e.w - mx.w);
        ushort4 f = featB4[src * 64 + lane];
        acc.x = fmaf(bf2f(f.x), ex.x, acc.x);
        acc.y = fmaf(bf2f(f.y), ex.y, acc.y);
        acc.z = fmaf(bf2f(f.z), ex.z, acc.z);
        acc.w = fmaf(bf2f(f.w), ex.w, acc.w);
    }
    float o = fmaxf(fmaf(acc.x, dr.x, bias[lane]), 0.f)
            + fmaxf(fmaf(acc.y, dr.y, bias[64 + lane]), 0.f)
            + fmaxf(fmaf(acc.z, dr.z, bias[128 + lane]), 0.f)
            + fmaxf(fmaf(acc.w, dr.w, bias[192 + lane]), 0.f);
    hout[row * 64 + lane] = o * 0.25f;
}

// ---------------- MLP head ----------------
#define MLP_BLOCKS 1250
#define MLP_CHUNKS 5
__global__ void k_mlp1_stats(const float* __restrict__ x, const float* __restrict__ W,
                             const float* __restrict__ b, float* __restrict__ z,
                             float* __restrict__ gsum, float* __restrict__ gsumsq) {
    __shared__ float xs[8][64];
    int tid = threadIdx.x;
    float bv = (tid < 200) ? b[tid] : 0.f;
    float s_ = 0.f, s2_ = 0.f;
    for (int chunk = 0; chunk < MLP_CHUNKS; chunk++) {
        int row0 = (blockIdx.x * MLP_CHUNKS + chunk) * 8;
        for (int i = tid; i < 512; i += 256)
            xs[i >> 6][i & 63] = x[(row0 + (i >> 6)) * 64 + (i & 63)];
        __syncthreads();
        if (tid < 200) {
            float acc[8];
#pragma unroll
            for (int r = 0; r < 8; r++) acc[r] = 0.f;
            for (int k = 0; k < 64; k++) {
                float w = W[k * 200 + tid];
#pragma unroll
                for (int r = 0; r < 8; r++) acc[r] = fmaf(xs[r][k], w, acc[r]);
            }
#pragma unroll
            for (int r = 0; r < 8; r++) {
                float v = fmaxf(acc[r] + bv, 0.f);
                z[(row0 + r) * 200 + tid] = v;
                s_ += v;
                s2_ = fmaf(v, v, s2_);
            }
        }
        __syncthreads();
    }
    if (tid < 200) {
        atomicAdd(&gsum[tid], s_);
        atomicAdd(&gsumsq[tid], s2_);
    }
}

// fold BN into the final linear
__global__ void k_bnprep(const float* __restrict__ gsum, const float* __restrict__ gsumsq,
                         const float* __restrict__ bn_g, const float* __restrict__ bn_b,
                         const float* __restrict__ mw2, const float* __restrict__ mb2,
                         float* __restrict__ w2p) {
    __shared__ float red0[256], red1[256];
    int c = threadIdx.x;
    float c0 = 0.f, c1 = 0.f;
    if (c < 200) {
        const float invN = 1.f / (float)N_NODES;
        float mu = gsum[c] * invN;
        float var = gsumsq[c] * invN - mu * mu;
        float alpha = bn_g[c] * rsqrtf(var + BN_EPS);
        float beta = bn_b[c] - mu * alpha;
        float w0 = mw2[c * 2], w1 = mw2[c * 2 + 1];
        w2p[c * 2] = alpha * w0;
        w2p[c * 2 + 1] = alpha * w1;
        c0 = beta * w0;
        c1 = beta * w1;
    }
    red0[c] = c0; red1[c] = c1;
    __syncthreads();
    for (int off = 128; off; off >>= 1) {
        if (c < off) { red0[c] += red0[c + off]; red1[c] += red1[c + off]; }
        __syncthreads();
    }
    if (c == 0) {
        w2p[400] = mb2[0] + red0[0];
        w2p[401] = mb2[1] + red1[0];
    }
}

__global__ void k_final(const float* __restrict__ z, const float* __restrict__ w2p, float* __restrict__ out) {
    int tid = threadIdx.x;
    int row = blockIdx.x * 4 + (tid >> 6);
    int lane = tid & 63;
    float a0 = 0.f, a1 = 0.f;
    for (int c = lane; c < 200; c += 64) {
        float v = z[row * 200 + c];
        a0 = fmaf(v, w2p[c * 2], a0);
        a1 = fmaf(v, w2p[c * 2 + 1], a1);
    }
#pragma unroll
    for (int off = 32; off; off >>= 1) {
        a0 += __shfl_xor(a0, off, 64);
        a1 += __shfl_xor(a1, off, 64);
    }
    if (lane == 0) {
        out[row * 2] = a0 + w2p[400];
        out[row * 2 + 1] = a1 + w2p[401];
    }
}

extern "C" void kernel_launch(void* const* d_in, const int* in_sizes, int n_in,
                              void* d_out, int out_size, void* d_ws, size_t ws_size,
                              hipStream_t stream) {
    const float* features = (const float*)d_in[0];
    const int*   ei       = (const int*)d_in[1];
    const float* W1  = (const float*)d_in[2];
    const float* al1 = (const float*)d_in[3];
    const float* ar1 = (const float*)d_in[4];
    const float* b1  = (const float*)d_in[5];
    const float* W2  = (const float*)d_in[6];
    const float* al2 = (const float*)d_in[7];
    const float* ar2 = (const float*)d_in[8];
    const float* b2  = (const float*)d_in[9];
    const float* mw1 = (const float*)d_in[10];
    const float* mb1 = (const float*)d_in[11];
    const float* bng = (const float*)d_in[12];
    const float* bnb = (const float*)d_in[13];
    const float* mw2 = (const float*)d_in[14];
    const float* mb2 = (const float*)d_in[15];
    float* out = (float*)d_out;

    // ---- workspace layout ----
    char* base = (char*)d_ws;
    size_t off = 0;
    auto alloc = [&](size_t bytes) -> char* {
        char* p = base + off;
        off = (off + bytes + 255) & ~(size_t)255;
        return p;
    };
    int*    deg    = (int*)alloc(N_NODES * 4);
    int*    rowptr = (int*)alloc((N_NODES + 1) * 4);
    int*    cursor = (int*)alloc(N_NODES * 4);
    int*    bsum   = (int*)alloc(256 * 4);
    int*    colidx = (int*)alloc(E_TOTAL * 4);
    ushort* featB  = (ushort*)alloc((size_t)N_NODES * 256 * 2);
    float*  el     = (float*)alloc((size_t)N_NODES * 4 * 4);
    float*  er     = (float*)alloc((size_t)N_NODES * 4 * 4);
    float*  h1     = (float*)alloc((size_t)N_NODES * 64 * 4);
    float*  h2     = (float*)alloc((size_t)N_NODES * 64 * 4);
    float*  z      = (float*)alloc((size_t)N_NODES * 200 * 4);
    float*  gsum   = (float*)alloc(256 * 4);
    float*  gsumsq = (float*)alloc(256 * 4);
    float*  w2p    = (float*)alloc(512 * 4);
    (void)ws_size; (void)in_sizes; (void)n_in; (void)out_size;

    const int NB_N = (N_NODES + 255) / 256;   // 196
    const int NB_E = (E_TOTAL + 255) / 256;   // 3321

    // CSR build
    k_zero<<<NB_N, 256, 0, stream>>>(deg, gsum, gsumsq);
    k_count<<<NB_E, 256, 0, stream>>>(ei, deg);
    k_scanA<<<NB_N, 256, 0, stream>>>(deg, rowptr, bsum);
    k_scanB<<<1, 256, 0, stream>>>(bsum, NB_N);
    k_scanC<<<NB_N, 256, 0, stream>>>(deg, rowptr, bsum, cursor);
    k_fill<<<NB_E, 256, 0, stream>>>(ei, cursor, colidx);

    // GAT layer 1
    k_gemm_feat<<<N_NODES / 8, 256, 0, stream>>>(features, W1, al1, ar1, featB, el, er);
    k_gat<<<N_NODES / 4, 256, 0, stream>>>((const float4*)el, (const float4*)er, rowptr, colidx, featB, b1, h1);

    // GAT layer 2
    k_gemm_feat<<<N_NODES / 8, 256, 0, stream>>>(h1, W2, al2, ar2, featB, el, er);
    k_gat<<<N_NODES / 4, 256, 0, stream>>>((const float4*)el, (const float4*)er, rowptr, colidx, featB, b2, h2);

    // MLP head
    k_mlp1_stats<<<MLP_BLOCKS, 256, 0, stream>>>(h2, mw1, mb1, z, gsum, gsumsq);
    k_bnprep<<<1, 256, 0, stream>>>(gsum, gsumsq, bng, bnb, mw2, mb2, w2p);
    k_final<<<N_NODES / 4, 256, 0, stream>>>(z, w2p, out);
}